// Round 13
// baseline (56.261 us; speedup 1.0000x reference)
//
#include <hip/hip_runtime.h>

// GraphAttentionRela: B=16, ATT=64, RELA=128, RNN=1024, HID=512
// Split-exp: tanh(p+q) = 1 - 2*rcp(exp2(K*p)*exp2(K*q)+1), K=2/ln2; score constants
// dropped (softmax shift-invariant); wws = -2*w_alpha so partials sum IS the score.
// K0 : A->bf16 | W->W^T bf16
// K1 : MFMA bf16 GEMM; epilogue Eq = exp2(K*(A@W+b_obj))
// K2a: stage exp2(K*p); partials[ba][hg][r] = sum_h (-2w_h)*rcp(Ep*Eq+1)
// K3 : per (b,d-tile,a-half): scores = sum_hg partials; softmax+mask+renorm (32 rows,
//      in LDS); out = weight^T @ rela   [k2b absorbed -> 4 kernels total]
// WS (disjoint): Abf[0,2) WT[2,3) Eq[3,5) partials[5,9) MB

constexpr int B_   = 16;
constexpr int ATT  = 64;
constexpr int RELA = 128;
constexpr int RNN  = 1024;
constexpr int HID  = 512;
constexpr int M_   = B_ * ATT;      // 1024
constexpr float EPS_ = 1e-8f;
constexpr float K2LN = 2.885390081777927f;   // 2/ln2
constexpr int RT  = 8;              // r per k2a block
constexpr int NRT = RELA / RT;      // 16
constexpr int HG  = 64;             // h per k2a block
constexpr int NHG = HID / HG;       // 8
constexpr int HW  = 16;             // h per wave

typedef short bf16x8 __attribute__((ext_vector_type(8)));
typedef float f32x4  __attribute__((ext_vector_type(4)));

__device__ __forceinline__ unsigned short f2bf(float f) {   // round-to-nearest-even
    unsigned u = __float_as_uint(f);
    u += 0x7FFFu + ((u >> 16) & 1u);
    return (unsigned short)(u >> 16);
}

// ---------------- K0: [0,512) A cast | [512,640) W transpose-cast
__global__ __launch_bounds__(256) void k0_pre(const float* __restrict__ A,
                                              const float* __restrict__ W,
                                              unsigned short* __restrict__ Abf,
                                              unsigned short* __restrict__ WT) {
    const int bid = blockIdx.x;
    const int tid = threadIdx.x;
    if (bid < 512) {
        const size_t idx = ((size_t)bid * 256 + tid) << 3;   // 8 floats
        const float4 f0 = *reinterpret_cast<const float4*>(&A[idx]);
        const float4 f1 = *reinterpret_cast<const float4*>(&A[idx + 4]);
        unsigned short us[8] = {f2bf(f0.x), f2bf(f0.y), f2bf(f0.z), f2bf(f0.w),
                                f2bf(f1.x), f2bf(f1.y), f2bf(f1.z), f2bf(f1.w)};
        *reinterpret_cast<uint4*>(&Abf[idx]) = *reinterpret_cast<uint4*>(us);
    } else {
        __shared__ float Ts[64][68];
        const int wb = bid - 512;
        const int k0 = (wb >> 3) << 6, n0 = (wb & 7) << 6;
        #pragma unroll
        for (int i = 0; i < 4; ++i) {
            const int r = (tid >> 4) + (i << 4);
            const int c4 = (tid & 15) << 2;
            *reinterpret_cast<float4*>(&Ts[r][c4]) =
                *reinterpret_cast<const float4*>(&W[(size_t)(k0 + r) * HID + n0 + c4]);
        }
        __syncthreads();
        const int n = tid >> 2, kq = (tid & 3) << 4;
        unsigned short us[16];
        #pragma unroll
        for (int e = 0; e < 16; ++e)
            us[e] = f2bf(Ts[kq + e][n]);
        unsigned short* dst = &WT[(size_t)(n0 + n) * RNN + k0 + kq];
        *reinterpret_cast<uint4*>(dst)     = *reinterpret_cast<uint4*>(us);
        *reinterpret_cast<uint4*>(dst + 8) = *reinterpret_cast<uint4*>(us + 8);
    }
}

// ---------------- K1: bf16 MFMA GEMM; epilogue Eq = exp2(K*(gemm+bias))
__global__ __launch_bounds__(256) void k1_mfma(const unsigned short* __restrict__ Abf,
                                               const unsigned short* __restrict__ WT,
                                               const float* __restrict__ b_obj,
                                               float* __restrict__ Eq) {
    const int tid = threadIdx.x;
    const int lane = tid & 63;
    const int wave = tid >> 6;
    const int m0 = (blockIdx.x << 5) + ((wave >> 1) << 4);
    const int n0 = (blockIdx.y << 5) + ((wave & 1) << 4);
    const int row  = lane & 15;
    const int koff = (lane >> 4) << 3;
    const unsigned short* ap = &Abf[(size_t)(m0 + row) * RNN + koff];
    const unsigned short* bp = &WT[(size_t)(n0 + row) * RNN + koff];
    f32x4 acc0 = {}, acc1 = {};
    #pragma unroll 4
    for (int k = 0; k < RNN; k += 64) {
        const bf16x8 a0 = *reinterpret_cast<const bf16x8*>(ap + k);
        const bf16x8 b0 = *reinterpret_cast<const bf16x8*>(bp + k);
        const bf16x8 a1 = *reinterpret_cast<const bf16x8*>(ap + k + 32);
        const bf16x8 b1 = *reinterpret_cast<const bf16x8*>(bp + k + 32);
        acc0 = __builtin_amdgcn_mfma_f32_16x16x32_bf16(a0, b0, acc0, 0, 0, 0);
        acc1 = __builtin_amdgcn_mfma_f32_16x16x32_bf16(a1, b1, acc1, 0, 0, 0);
    }
    const int dcol = lane & 15;
    const int drow0 = (lane >> 4) << 2;
    const float bias = b_obj[n0 + dcol];
    #pragma unroll
    for (int v = 0; v < 4; ++v)
        Eq[(size_t)(m0 + drow0 + v) * HID + n0 + dcol] =
            __builtin_amdgcn_exp2f((acc0[v] + acc1[v] + bias) * K2LN);
}

// ---------------- K2a: stage exp2(K*p); 4-op inner loop. grid (16,16,8)=2048, 256 thr
__global__ __launch_bounds__(256, 8) void k2a_scores(const float* __restrict__ Eq,
                                                     const float* __restrict__ p_rela,
                                                     const float* __restrict__ w_alpha,
                                                     float* __restrict__ partials) {
    const int b  = blockIdx.x;
    const int rt = blockIdx.y;
    const int hg = blockIdx.z;
    const int tid = threadIdx.x;
    const int lane = tid & 63;      // = a
    const int wave = tid >> 6;

    __shared__ float ps[RT][HG];        // 2 KB: exp2(K*p) tile
    __shared__ float wws[HG];           // -2*w_alpha for this hg
    __shared__ float red[4][RT][ATT];   // 8 KB, [wave][r][a] lane-contiguous

    if (tid < 128) {   // stage p tile with on-the-fly exp2: 8 rows x 16 float4
        const int row = tid >> 4, c4 = (tid & 15) << 2;
        float4 v = *reinterpret_cast<const float4*>(
            &p_rela[((size_t)b * RELA + rt * RT + row) * HID + hg * HG + c4]);
        v.x = __builtin_amdgcn_exp2f(v.x * K2LN);
        v.y = __builtin_amdgcn_exp2f(v.y * K2LN);
        v.z = __builtin_amdgcn_exp2f(v.z * K2LN);
        v.w = __builtin_amdgcn_exp2f(v.w * K2LN);
        *reinterpret_cast<float4*>(&ps[row][c4]) = v;
    } else if (tid < 144) {
        const int c4 = (tid - 128) << 2;
        float4 w = *reinterpret_cast<const float4*>(&w_alpha[hg * HG + c4]);
        w.x *= -2.f; w.y *= -2.f; w.z *= -2.f; w.w *= -2.f;
        *reinterpret_cast<float4*>(&wws[c4]) = w;
    }
    const int hbase = hg * HG + wave * HW;
    float4 eq[4];
    #pragma unroll
    for (int i = 0; i < 4; ++i)
        eq[i] = *reinterpret_cast<const float4*>(&Eq[(size_t)((b << 6) + lane) * HID + hbase + (i << 2)]);
    __syncthreads();

    float acc[RT] = {};
    #pragma unroll
    for (int i = 0; i < 4; ++i) {
        const float qq[4] = {eq[i].x, eq[i].y, eq[i].z, eq[i].w};
        const float4 w4 = *reinterpret_cast<const float4*>(&wws[wave * HW + (i << 2)]);  // broadcast
        const float ww[4] = {w4.x, w4.y, w4.z, w4.w};
        #pragma unroll
        for (int r = 0; r < RT; ++r) {
            const float4 p4 = *reinterpret_cast<const float4*>(&ps[r][wave * HW + (i << 2)]);  // broadcast
            const float pp[4] = {p4.x, p4.y, p4.z, p4.w};
            #pragma unroll
            for (int j = 0; j < 4; ++j) {
                const float e = pp[j] * qq[j];                       // exp2(K*(p+q))
                acc[r] = fmaf(ww[j], __builtin_amdgcn_rcpf(e + 1.f), acc[r]);
            }
        }
    }

    #pragma unroll
    for (int r = 0; r < RT; ++r)
        red[wave][r][lane] = acc[r];    // conflict-free
    __syncthreads();

    const int a = tid & 63, rg = tid >> 6;
    float2 o;
    o.x = red[0][rg * 2][a] + red[1][rg * 2][a] + red[2][rg * 2][a] + red[3][rg * 2][a];
    o.y = red[0][rg * 2 + 1][a] + red[1][rg * 2 + 1][a] + red[2][rg * 2 + 1][a] + red[3][rg * 2 + 1][a];
    const size_t ba = (size_t)(b << 6) + a;
    *reinterpret_cast<float2*>(&partials[(ba * NHG + hg) * RELA + rt * RT + rg * 2]) = o;
}

// ---------------- K3: sum partials + softmax + mask + renorm (32 rows in LDS) + wsum
// grid (B, RNN/64, 2) = 512 blocks, 256 thr; block owns 32 a's x 64 d's
__global__ __launch_bounds__(256) void k3_softmax_wsum(const float* __restrict__ partials,
                                                       const int* __restrict__ masks,
                                                       const float* __restrict__ rela,
                                                       float* __restrict__ out) {
    const int b = blockIdx.x;
    const int d_base = blockIdx.y << 6;
    const int ah = blockIdx.z;          // a-half
    const int tid = threadIdx.x;
    const int lane = tid & 63;
    const int wave = tid >> 6;

    __shared__ float ws_s[32][132];     // scores -> weights in place
    __shared__ float rs[32 * 64];

    // stage scores: ws_s[la][r] = sum_hg partials[(b*64+ah*32+la)][hg][r]  (pre-negated)
    #pragma unroll
    for (int i = 0; i < 4; ++i) {
        const int fi = tid + (i << 8);            // 1024 float4 total
        const int la = fi >> 5, r4 = (fi & 31) << 2;
        const float* pp = &partials[(size_t)((b << 6) + (ah << 5) + la) * NHG * RELA + r4];
        float4 s = {0.f, 0.f, 0.f, 0.f};
        #pragma unroll
        for (int hg = 0; hg < NHG; ++hg) {
            const float4 v = *reinterpret_cast<const float4*>(&pp[hg * RELA]);
            s.x += v.x; s.y += v.y; s.z += v.z; s.w += v.w;
        }
        *reinterpret_cast<float4*>(&ws_s[la][r4]) = s;
    }
    __syncthreads();

    // softmax+mask+renorm: wave w owns rows la = w*8..w*8+7
    #pragma unroll 1
    for (int aa = 0; aa < 8; ++aa) {
        const int la = (wave << 3) + aa;
        const int ga = (b << 6) + (ah << 5) + la;   // global (b,a) row
        const float s0 = ws_s[la][lane], s1 = ws_s[la][lane + 64];
        float m = fmaxf(s0, s1);
        #pragma unroll
        for (int off = 32; off > 0; off >>= 1)
            m = fmaxf(m, __shfl_xor(m, off));
        const float e0 = __expf(s0 - m), e1 = __expf(s1 - m);
        float sum = e0 + e1;
        #pragma unroll
        for (int off = 32; off > 0; off >>= 1)
            sum += __shfl_xor(sum, off);
        const float inv = __builtin_amdgcn_rcpf(sum);
        const float m0 = (float)masks[(size_t)ga * RELA + lane];
        const float m1 = (float)masks[(size_t)ga * RELA + lane + 64];
        const float w0 = e0 * inv * m0;
        const float w1 = e1 * inv * m1;
        float ms = w0 + w1;
        #pragma unroll
        for (int off = 32; off > 0; off >>= 1)
            ms += __shfl_xor(ms, off);
        const float inv2 = 1.f / (ms + EPS_);
        ws_s[la][lane]      = w0 * inv2;
        ws_s[la][lane + 64] = w1 * inv2;
    }

    // weighted sum: thread = (col = float4-d, la0 = 2 local a's)
    const int col = tid & 15;
    const int la0 = (tid >> 4) << 1;
    float4 acc[2] = {};
    for (int rc = 0; rc < 4; ++rc) {
        __syncthreads();
        #pragma unroll
        for (int i = 0; i < 2; ++i) {
            const int fi = tid + (i << 8);
            const int rr = fi >> 4, c = fi & 15;
            *reinterpret_cast<float4*>(&rs[(rr << 6) + (c << 2)]) =
                *reinterpret_cast<const float4*>(&rela[((size_t)b * RELA + (rc << 5) + rr) * RNN + d_base + (c << 2)]);
        }
        __syncthreads();
        #pragma unroll 8
        for (int rr = 0; rr < 32; ++rr) {
            const float4 x = *reinterpret_cast<const float4*>(&rs[(rr << 6) + (col << 2)]);
            const int r = (rc << 5) + rr;
            #pragma unroll
            for (int ai = 0; ai < 2; ++ai) {
                const float wv = ws_s[la0 + ai][r];
                acc[ai].x = fmaf(wv, x.x, acc[ai].x);
                acc[ai].y = fmaf(wv, x.y, acc[ai].y);
                acc[ai].z = fmaf(wv, x.z, acc[ai].z);
                acc[ai].w = fmaf(wv, x.w, acc[ai].w);
            }
        }
    }
    #pragma unroll
    for (int ai = 0; ai < 2; ++ai)
        *reinterpret_cast<float4*>(
            &out[((size_t)(b << 6) + (ah << 5) + la0 + ai) * RNN + d_base + (col << 2)]) = acc[ai];
}

extern "C" void kernel_launch(void* const* d_in, const int* in_sizes, int n_in,
                              void* d_out, int out_size, void* d_ws, size_t ws_size,
                              hipStream_t stream) {
    const float* obj_vecs = (const float*)d_in[0];
    const float* rela     = (const float*)d_in[1];
    const float* p_rela   = (const float*)d_in[2];
    const float* W_obj    = (const float*)d_in[3];
    const float* b_obj    = (const float*)d_in[4];
    const float* w_alpha  = (const float*)d_in[5];
    // d_in[6] (b_alpha): softmax-shift-invariant, unused
    const int*   masks    = (const int*)d_in[7];
    float* out = (float*)d_out;

    char* ws = (char*)d_ws;
    unsigned short* Abf = (unsigned short*)(ws);                 // [0, 2MB)
    unsigned short* WT  = (unsigned short*)(ws + (2u << 20));    // [2MB, 3MB)
    float* Eq           = (float*)(ws + (3u << 20));             // [3MB, 5MB)
    float* partials     = (float*)(ws + (5u << 20));             // [5MB, 9MB)

    k0_pre<<<dim3(640), 256, 0, stream>>>(obj_vecs, W_obj, Abf, WT);
    k1_mfma<<<dim3(M_ / 32, HID / 32), 256, 0, stream>>>(Abf, WT, b_obj, Eq);
    k2a_scores<<<dim3(B_, NRT, NHG), 256, 0, stream>>>(Eq, p_rela, w_alpha, partials);
    k3_softmax_wsum<<<dim3(B_, RNN / 64, 2), 256, 0, stream>>>(partials, masks, rela, out);
}

// Round 14
// 54.405 us; speedup vs baseline: 1.0341x; 1.0341x over previous
//
#include <hip/hip_runtime.h>

// GraphAttentionRela: B=16, ATT=64, RELA=128, RNN=1024, HID=512
// R12 skeleton (proven best, 47.5us) with k0's A-cast folded into k1 (inline fp32->bf16).
// Split-exp: tanh(p+q) = 1 - 2*rcp(exp2(K*p)*exp2(K*q)+1), K=2/ln2; score constants
// dropped (softmax shift-invariant); wws = -2*w_alpha so partials sum IS the score.
// K0 : W -> W^T bf16 (128 blocks only)
// K1 : MFMA bf16 GEMM, A read fp32 + in-register cvt; epilogue Eq = exp2(K*(A@W+b_obj))
// K2a: stage exp2(K*p); partials[ba][hg][r] = sum_h (-2w_h)*rcp(Ep*Eq+1)
// K2b: s = sum_hg partials; softmax+mask+renorm -> weight[b][a][r]
// K3 : out[b] = weight^T @ rela[b], a-split x2
// WS (disjoint): WT[0,1) Eq[1,3) partials[3,7) weight[7,7.5) MB

constexpr int B_   = 16;
constexpr int ATT  = 64;
constexpr int RELA = 128;
constexpr int RNN  = 1024;
constexpr int HID  = 512;
constexpr int M_   = B_ * ATT;      // 1024
constexpr float EPS_ = 1e-8f;
constexpr float K2LN = 2.885390081777927f;   // 2/ln2
constexpr int RT  = 8;              // r per k2a block
constexpr int NRT = RELA / RT;      // 16
constexpr int HG  = 64;             // h per k2a block
constexpr int NHG = HID / HG;       // 8
constexpr int HW  = 16;             // h per wave

typedef short bf16x8 __attribute__((ext_vector_type(8)));
typedef float f32x4  __attribute__((ext_vector_type(4)));

__device__ __forceinline__ unsigned short f2bf(float f) {   // round-to-nearest-even
    unsigned u = __float_as_uint(f);
    u += 0x7FFFu + ((u >> 16) & 1u);
    return (unsigned short)(u >> 16);
}

__device__ __forceinline__ bf16x8 cvt8(float4 lo, float4 hi) {
    bf16x8 r;
    r[0] = (short)f2bf(lo.x); r[1] = (short)f2bf(lo.y);
    r[2] = (short)f2bf(lo.z); r[3] = (short)f2bf(lo.w);
    r[4] = (short)f2bf(hi.x); r[5] = (short)f2bf(hi.y);
    r[6] = (short)f2bf(hi.z); r[7] = (short)f2bf(hi.w);
    return r;
}

// ---------------- K0: W[k][n] -> WT[n][k] bf16. grid 128, 256 thr
__global__ __launch_bounds__(256) void k0_wt(const float* __restrict__ W,
                                             unsigned short* __restrict__ WT) {
    __shared__ float Ts[64][68];
    const int wb = blockIdx.x;
    const int tid = threadIdx.x;
    const int k0 = (wb >> 3) << 6, n0 = (wb & 7) << 6;
    #pragma unroll
    for (int i = 0; i < 4; ++i) {
        const int r = (tid >> 4) + (i << 4);
        const int c4 = (tid & 15) << 2;
        *reinterpret_cast<float4*>(&Ts[r][c4]) =
            *reinterpret_cast<const float4*>(&W[(size_t)(k0 + r) * HID + n0 + c4]);
    }
    __syncthreads();
    const int n = tid >> 2, kq = (tid & 3) << 4;
    unsigned short us[16];
    #pragma unroll
    for (int e = 0; e < 16; ++e)
        us[e] = f2bf(Ts[kq + e][n]);
    unsigned short* dst = &WT[(size_t)(n0 + n) * RNN + k0 + kq];
    *reinterpret_cast<uint4*>(dst)     = *reinterpret_cast<uint4*>(us);
    *reinterpret_cast<uint4*>(dst + 8) = *reinterpret_cast<uint4*>(us + 8);
}

// ---------------- K1: bf16 MFMA GEMM, A fp32 + inline cvt; epilogue Eq = exp2(K*(..+b))
// grid (32,16), 256 thr (4 waves, one 16x16 tile each)
__global__ __launch_bounds__(256) void k1_mfma(const float* __restrict__ A,
                                               const unsigned short* __restrict__ WT,
                                               const float* __restrict__ b_obj,
                                               float* __restrict__ Eq) {
    const int tid = threadIdx.x;
    const int lane = tid & 63;
    const int wave = tid >> 6;
    const int m0 = (blockIdx.x << 5) + ((wave >> 1) << 4);
    const int n0 = (blockIdx.y << 5) + ((wave & 1) << 4);
    const int row  = lane & 15;
    const int koff = (lane >> 4) << 3;
    const float* ap = &A[(size_t)(m0 + row) * RNN + koff];
    const unsigned short* bp = &WT[(size_t)(n0 + row) * RNN + koff];
    f32x4 acc0 = {}, acc1 = {};
    #pragma unroll 4
    for (int k = 0; k < RNN; k += 64) {
        const float4 af0 = *reinterpret_cast<const float4*>(ap + k);
        const float4 af1 = *reinterpret_cast<const float4*>(ap + k + 4);
        const float4 af2 = *reinterpret_cast<const float4*>(ap + k + 32);
        const float4 af3 = *reinterpret_cast<const float4*>(ap + k + 36);
        const bf16x8 a0 = cvt8(af0, af1);
        const bf16x8 a1 = cvt8(af2, af3);
        const bf16x8 b0 = *reinterpret_cast<const bf16x8*>(bp + k);
        const bf16x8 b1 = *reinterpret_cast<const bf16x8*>(bp + k + 32);
        acc0 = __builtin_amdgcn_mfma_f32_16x16x32_bf16(a0, b0, acc0, 0, 0, 0);
        acc1 = __builtin_amdgcn_mfma_f32_16x16x32_bf16(a1, b1, acc1, 0, 0, 0);
    }
    const int dcol = lane & 15;
    const int drow0 = (lane >> 4) << 2;
    const float bias = b_obj[n0 + dcol];
    #pragma unroll
    for (int v = 0; v < 4; ++v)
        Eq[(size_t)(m0 + drow0 + v) * HID + n0 + dcol] =
            __builtin_amdgcn_exp2f((acc0[v] + acc1[v] + bias) * K2LN);
}

// ---------------- K2a: stage exp2(K*p); 4-op inner loop. grid (16,16,8)=2048, 256 thr
__global__ __launch_bounds__(256, 8) void k2a_scores(const float* __restrict__ Eq,
                                                     const float* __restrict__ p_rela,
                                                     const float* __restrict__ w_alpha,
                                                     float* __restrict__ partials) {
    const int b  = blockIdx.x;
    const int rt = blockIdx.y;
    const int hg = blockIdx.z;
    const int tid = threadIdx.x;
    const int lane = tid & 63;      // = a
    const int wave = tid >> 6;

    __shared__ float ps[RT][HG];        // 2 KB: exp2(K*p) tile
    __shared__ float wws[HG];           // -2*w_alpha for this hg
    __shared__ float red[4][RT][ATT];   // 8 KB, [wave][r][a] lane-contiguous

    if (tid < 128) {   // stage p tile with on-the-fly exp2: 8 rows x 16 float4
        const int row = tid >> 4, c4 = (tid & 15) << 2;
        float4 v = *reinterpret_cast<const float4*>(
            &p_rela[((size_t)b * RELA + rt * RT + row) * HID + hg * HG + c4]);
        v.x = __builtin_amdgcn_exp2f(v.x * K2LN);
        v.y = __builtin_amdgcn_exp2f(v.y * K2LN);
        v.z = __builtin_amdgcn_exp2f(v.z * K2LN);
        v.w = __builtin_amdgcn_exp2f(v.w * K2LN);
        *reinterpret_cast<float4*>(&ps[row][c4]) = v;
    } else if (tid < 144) {
        const int c4 = (tid - 128) << 2;
        float4 w = *reinterpret_cast<const float4*>(&w_alpha[hg * HG + c4]);
        w.x *= -2.f; w.y *= -2.f; w.z *= -2.f; w.w *= -2.f;
        *reinterpret_cast<float4*>(&wws[c4]) = w;
    }
    const int hbase = hg * HG + wave * HW;
    float4 eq[4];
    #pragma unroll
    for (int i = 0; i < 4; ++i)
        eq[i] = *reinterpret_cast<const float4*>(&Eq[(size_t)((b << 6) + lane) * HID + hbase + (i << 2)]);
    __syncthreads();

    float acc[RT] = {};
    #pragma unroll
    for (int i = 0; i < 4; ++i) {
        const float qq[4] = {eq[i].x, eq[i].y, eq[i].z, eq[i].w};
        const float4 w4 = *reinterpret_cast<const float4*>(&wws[wave * HW + (i << 2)]);  // broadcast
        const float ww[4] = {w4.x, w4.y, w4.z, w4.w};
        #pragma unroll
        for (int r = 0; r < RT; ++r) {
            const float4 p4 = *reinterpret_cast<const float4*>(&ps[r][wave * HW + (i << 2)]);  // broadcast
            const float pp[4] = {p4.x, p4.y, p4.z, p4.w};
            #pragma unroll
            for (int j = 0; j < 4; ++j) {
                const float e = pp[j] * qq[j];                       // exp2(K*(p+q))
                acc[r] = fmaf(ww[j], __builtin_amdgcn_rcpf(e + 1.f), acc[r]);
            }
        }
    }

    #pragma unroll
    for (int r = 0; r < RT; ++r)
        red[wave][r][lane] = acc[r];    // conflict-free
    __syncthreads();

    const int a = tid & 63, rg = tid >> 6;
    float2 o;
    o.x = red[0][rg * 2][a] + red[1][rg * 2][a] + red[2][rg * 2][a] + red[3][rg * 2][a];
    o.y = red[0][rg * 2 + 1][a] + red[1][rg * 2 + 1][a] + red[2][rg * 2 + 1][a] + red[3][rg * 2 + 1][a];
    const size_t ba = (size_t)(b << 6) + a;
    *reinterpret_cast<float2*>(&partials[(ba * NHG + hg) * RELA + rt * RT + rg * 2]) = o;
}

// ---------------- K2b: s = sum partials (pre-negated); softmax+mask+renorm -> weight
__global__ __launch_bounds__(256) void k2b_softmax(const float* __restrict__ partials,
                                                   const int* __restrict__ masks,
                                                   float* __restrict__ weight) {
    const int tid = threadIdx.x;
    const int lane = tid & 63;
    const int wave = tid >> 6;
    const int ba = (blockIdx.x << 2) + wave;

    const float* pp = &partials[(size_t)ba * NHG * RELA];
    float s0 = 0.f, s1 = 0.f;
    #pragma unroll
    for (int hs = 0; hs < NHG; ++hs) {
        s0 += pp[hs * RELA + lane];
        s1 += pp[hs * RELA + lane + 64];
    }

    float m = fmaxf(s0, s1);
    #pragma unroll
    for (int off = 32; off > 0; off >>= 1)
        m = fmaxf(m, __shfl_xor(m, off));
    const float e0 = __expf(s0 - m), e1 = __expf(s1 - m);
    float sum = e0 + e1;
    #pragma unroll
    for (int off = 32; off > 0; off >>= 1)
        sum += __shfl_xor(sum, off);
    const float inv = 1.f / sum;
    const float m0 = (float)masks[(size_t)ba * RELA + lane];
    const float m1 = (float)masks[(size_t)ba * RELA + lane + 64];
    const float w0 = e0 * inv * m0;
    const float w1 = e1 * inv * m1;
    float ms = w0 + w1;
    #pragma unroll
    for (int off = 32; off > 0; off >>= 1)
        ms += __shfl_xor(ms, off);
    const float inv2 = 1.f / (ms + EPS_);
    weight[(size_t)ba * RELA + lane]      = w0 * inv2;
    weight[(size_t)ba * RELA + lane + 64] = w1 * inv2;
}

// ---------------- K3: out[b] = weight^T @ rela[b]; grid (B, RNN/64, 2), 256 thr
// a-split x2: each block does 32 a's x 64 d's -> 2 waves/SIMD occupancy
__global__ __launch_bounds__(256) void k3_wsum(const float* __restrict__ weight,
                                               const float* __restrict__ rela,
                                               float* __restrict__ out) {
    const int b = blockIdx.x;
    const int d_base = blockIdx.y << 6;
    const int ah = blockIdx.z;          // a-half: 0 or 1
    const int tid = threadIdx.x;
    const int col = tid & 15;           // float4 column in 64-d tile
    const int la0 = (tid >> 4) << 1;    // local a (2 per thread), 0..30

    __shared__ float ws_s[32][132];     // [la][r]
    __shared__ float rs[32 * 64];
    #pragma unroll
    for (int i = 0; i < 4; ++i) {       // stage 32 rows x 128 = 1024 float4
        const int fi = tid + (i << 8);
        const int a = fi >> 5, r0 = (fi & 31) << 2;
        *reinterpret_cast<float4*>(&ws_s[a][r0]) =
            *reinterpret_cast<const float4*>(&weight[((size_t)b * ATT + (ah << 5) + a) * RELA + r0]);
    }
    float4 acc[2] = {};
    for (int rc = 0; rc < 4; ++rc) {
        __syncthreads();
        #pragma unroll
        for (int i = 0; i < 2; ++i) {
            const int fi = tid + (i << 8);
            const int rr = fi >> 4, c = fi & 15;
            *reinterpret_cast<float4*>(&rs[(rr << 6) + (c << 2)]) =
                *reinterpret_cast<const float4*>(&rela[((size_t)b * RELA + (rc << 5) + rr) * RNN + d_base + (c << 2)]);
        }
        __syncthreads();
        #pragma unroll 8
        for (int rr = 0; rr < 32; ++rr) {
            const float4 x = *reinterpret_cast<const float4*>(&rs[(rr << 6) + (col << 2)]);
            const int r = (rc << 5) + rr;
            #pragma unroll
            for (int ai = 0; ai < 2; ++ai) {
                const float wv = ws_s[la0 + ai][r];
                acc[ai].x = fmaf(wv, x.x, acc[ai].x);
                acc[ai].y = fmaf(wv, x.y, acc[ai].y);
                acc[ai].z = fmaf(wv, x.z, acc[ai].z);
                acc[ai].w = fmaf(wv, x.w, acc[ai].w);
            }
        }
    }
    #pragma unroll
    for (int ai = 0; ai < 2; ++ai)
        *reinterpret_cast<float4*>(
            &out[((size_t)(b << 6) + (ah << 5) + la0 + ai) * RNN + d_base + (col << 2)]) = acc[ai];
}

extern "C" void kernel_launch(void* const* d_in, const int* in_sizes, int n_in,
                              void* d_out, int out_size, void* d_ws, size_t ws_size,
                              hipStream_t stream) {
    const float* obj_vecs = (const float*)d_in[0];
    const float* rela     = (const float*)d_in[1];
    const float* p_rela   = (const float*)d_in[2];
    const float* W_obj    = (const float*)d_in[3];
    const float* b_obj    = (const float*)d_in[4];
    const float* w_alpha  = (const float*)d_in[5];
    // d_in[6] (b_alpha): softmax-shift-invariant, unused
    const int*   masks    = (const int*)d_in[7];
    float* out = (float*)d_out;

    char* ws = (char*)d_ws;
    unsigned short* WT = (unsigned short*)(ws);            // [0, 1MB)
    float* Eq          = (float*)(ws + (1u << 20));        // [1MB, 3MB)
    float* partials    = (float*)(ws + (3u << 20));        // [3MB, 7MB)
    float* weight      = (float*)(ws + (7u << 20));        // [7MB, 7.5MB)

    k0_wt<<<dim3(128), 256, 0, stream>>>(W_obj, WT);
    k1_mfma<<<dim3(M_ / 32, HID / 32), 256, 0, stream>>>(obj_vecs, WT, b_obj, Eq);
    k2a_scores<<<dim3(B_, NRT, NHG), 256, 0, stream>>>(Eq, p_rela, w_alpha, partials);
    k2b_softmax<<<dim3(M_ / 4), 256, 0, stream>>>(partials, masks, weight);
    k3_wsum<<<dim3(B_, RNN / 64, 2), 256, 0, stream>>>(weight, rela, out);
}

// Round 15
// 47.519 us; speedup vs baseline: 1.1840x; 1.1449x over previous
//
#include <hip/hip_runtime.h>

// GraphAttentionRela: B=16, ATT=64, RELA=128, RNN=1024, HID=512
// R12 verbatim (measured best: 47.5us).
// Split-exp: tanh(p+q) = 1 - 2*rcp(exp2(K*p)*exp2(K*q)+1), K=2/ln2; score constants
// dropped (softmax shift-invariant); wws = -2*w_alpha so partials sum IS the score.
// K0 : A->bf16 | W->W^T bf16
// K1 : MFMA bf16 GEMM; epilogue Eq = exp2(K*(A@W+b_obj))
// K2a: stage exp2(K*p); partials[ba][hg][r] = sum_h (-2w_h)*rcp(Ep*Eq+1)
// K2b: s = sum_hg partials; softmax+mask+renorm -> weight[b][a][r]
// K3 : out[b] = weight^T @ rela[b], a-split x2
// WS (disjoint): Abf[0,2) WT[2,3) Eq[3,5) partials[5,9) weight[9,9.5) MB

constexpr int B_   = 16;
constexpr int ATT  = 64;
constexpr int RELA = 128;
constexpr int RNN  = 1024;
constexpr int HID  = 512;
constexpr int M_   = B_ * ATT;      // 1024
constexpr float EPS_ = 1e-8f;
constexpr float K2LN = 2.885390081777927f;   // 2/ln2
constexpr int RT  = 8;              // r per k2a block
constexpr int NRT = RELA / RT;      // 16
constexpr int HG  = 64;             // h per k2a block
constexpr int NHG = HID / HG;       // 8
constexpr int HW  = 16;             // h per wave

typedef short bf16x8 __attribute__((ext_vector_type(8)));
typedef float f32x4  __attribute__((ext_vector_type(4)));

__device__ __forceinline__ unsigned short f2bf(float f) {   // round-to-nearest-even
    unsigned u = __float_as_uint(f);
    u += 0x7FFFu + ((u >> 16) & 1u);
    return (unsigned short)(u >> 16);
}

// ---------------- K0: [0,512) A cast | [512,640) W transpose-cast
__global__ __launch_bounds__(256) void k0_pre(const float* __restrict__ A,
                                              const float* __restrict__ W,
                                              unsigned short* __restrict__ Abf,
                                              unsigned short* __restrict__ WT) {
    const int bid = blockIdx.x;
    const int tid = threadIdx.x;
    if (bid < 512) {
        const size_t idx = ((size_t)bid * 256 + tid) << 3;   // 8 floats
        const float4 f0 = *reinterpret_cast<const float4*>(&A[idx]);
        const float4 f1 = *reinterpret_cast<const float4*>(&A[idx + 4]);
        unsigned short us[8] = {f2bf(f0.x), f2bf(f0.y), f2bf(f0.z), f2bf(f0.w),
                                f2bf(f1.x), f2bf(f1.y), f2bf(f1.z), f2bf(f1.w)};
        *reinterpret_cast<uint4*>(&Abf[idx]) = *reinterpret_cast<uint4*>(us);
    } else {
        __shared__ float Ts[64][68];
        const int wb = bid - 512;
        const int k0 = (wb >> 3) << 6, n0 = (wb & 7) << 6;
        #pragma unroll
        for (int i = 0; i < 4; ++i) {
            const int r = (tid >> 4) + (i << 4);
            const int c4 = (tid & 15) << 2;
            *reinterpret_cast<float4*>(&Ts[r][c4]) =
                *reinterpret_cast<const float4*>(&W[(size_t)(k0 + r) * HID + n0 + c4]);
        }
        __syncthreads();
        const int n = tid >> 2, kq = (tid & 3) << 4;
        unsigned short us[16];
        #pragma unroll
        for (int e = 0; e < 16; ++e)
            us[e] = f2bf(Ts[kq + e][n]);
        unsigned short* dst = &WT[(size_t)(n0 + n) * RNN + k0 + kq];
        *reinterpret_cast<uint4*>(dst)     = *reinterpret_cast<uint4*>(us);
        *reinterpret_cast<uint4*>(dst + 8) = *reinterpret_cast<uint4*>(us + 8);
    }
}

// ---------------- K1: bf16 MFMA GEMM; epilogue Eq = exp2(K*(gemm+bias))
__global__ __launch_bounds__(256) void k1_mfma(const unsigned short* __restrict__ Abf,
                                               const unsigned short* __restrict__ WT,
                                               const float* __restrict__ b_obj,
                                               float* __restrict__ Eq) {
    const int tid = threadIdx.x;
    const int lane = tid & 63;
    const int wave = tid >> 6;
    const int m0 = (blockIdx.x << 5) + ((wave >> 1) << 4);
    const int n0 = (blockIdx.y << 5) + ((wave & 1) << 4);
    const int row  = lane & 15;
    const int koff = (lane >> 4) << 3;
    const unsigned short* ap = &Abf[(size_t)(m0 + row) * RNN + koff];
    const unsigned short* bp = &WT[(size_t)(n0 + row) * RNN + koff];
    f32x4 acc0 = {}, acc1 = {};
    #pragma unroll 4
    for (int k = 0; k < RNN; k += 64) {
        const bf16x8 a0 = *reinterpret_cast<const bf16x8*>(ap + k);
        const bf16x8 b0 = *reinterpret_cast<const bf16x8*>(bp + k);
        const bf16x8 a1 = *reinterpret_cast<const bf16x8*>(ap + k + 32);
        const bf16x8 b1 = *reinterpret_cast<const bf16x8*>(bp + k + 32);
        acc0 = __builtin_amdgcn_mfma_f32_16x16x32_bf16(a0, b0, acc0, 0, 0, 0);
        acc1 = __builtin_amdgcn_mfma_f32_16x16x32_bf16(a1, b1, acc1, 0, 0, 0);
    }
    const int dcol = lane & 15;
    const int drow0 = (lane >> 4) << 2;
    const float bias = b_obj[n0 + dcol];
    #pragma unroll
    for (int v = 0; v < 4; ++v)
        Eq[(size_t)(m0 + drow0 + v) * HID + n0 + dcol] =
            __builtin_amdgcn_exp2f((acc0[v] + acc1[v] + bias) * K2LN);
}

// ---------------- K2a: stage exp2(K*p); 4-op inner loop. grid (16,16,8)=2048, 256 thr
__global__ __launch_bounds__(256, 8) void k2a_scores(const float* __restrict__ Eq,
                                                     const float* __restrict__ p_rela,
                                                     const float* __restrict__ w_alpha,
                                                     float* __restrict__ partials) {
    const int b  = blockIdx.x;
    const int rt = blockIdx.y;
    const int hg = blockIdx.z;
    const int tid = threadIdx.x;
    const int lane = tid & 63;      // = a
    const int wave = tid >> 6;

    __shared__ float ps[RT][HG];        // 2 KB: exp2(K*p) tile
    __shared__ float wws[HG];           // -2*w_alpha for this hg
    __shared__ float red[4][RT][ATT];   // 8 KB, [wave][r][a] lane-contiguous

    if (tid < 128) {   // stage p tile with on-the-fly exp2: 8 rows x 16 float4
        const int row = tid >> 4, c4 = (tid & 15) << 2;
        float4 v = *reinterpret_cast<const float4*>(
            &p_rela[((size_t)b * RELA + rt * RT + row) * HID + hg * HG + c4]);
        v.x = __builtin_amdgcn_exp2f(v.x * K2LN);
        v.y = __builtin_amdgcn_exp2f(v.y * K2LN);
        v.z = __builtin_amdgcn_exp2f(v.z * K2LN);
        v.w = __builtin_amdgcn_exp2f(v.w * K2LN);
        *reinterpret_cast<float4*>(&ps[row][c4]) = v;
    } else if (tid < 144) {
        const int c4 = (tid - 128) << 2;
        float4 w = *reinterpret_cast<const float4*>(&w_alpha[hg * HG + c4]);
        w.x *= -2.f; w.y *= -2.f; w.z *= -2.f; w.w *= -2.f;
        *reinterpret_cast<float4*>(&wws[c4]) = w;
    }
    const int hbase = hg * HG + wave * HW;
    float4 eq[4];
    #pragma unroll
    for (int i = 0; i < 4; ++i)
        eq[i] = *reinterpret_cast<const float4*>(&Eq[(size_t)((b << 6) + lane) * HID + hbase + (i << 2)]);
    __syncthreads();

    float acc[RT] = {};
    #pragma unroll
    for (int i = 0; i < 4; ++i) {
        const float qq[4] = {eq[i].x, eq[i].y, eq[i].z, eq[i].w};
        const float4 w4 = *reinterpret_cast<const float4*>(&wws[wave * HW + (i << 2)]);  // broadcast
        const float ww[4] = {w4.x, w4.y, w4.z, w4.w};
        #pragma unroll
        for (int r = 0; r < RT; ++r) {
            const float4 p4 = *reinterpret_cast<const float4*>(&ps[r][wave * HW + (i << 2)]);  // broadcast
            const float pp[4] = {p4.x, p4.y, p4.z, p4.w};
            #pragma unroll
            for (int j = 0; j < 4; ++j) {
                const float e = pp[j] * qq[j];                       // exp2(K*(p+q))
                acc[r] = fmaf(ww[j], __builtin_amdgcn_rcpf(e + 1.f), acc[r]);
            }
        }
    }

    #pragma unroll
    for (int r = 0; r < RT; ++r)
        red[wave][r][lane] = acc[r];    // conflict-free
    __syncthreads();

    const int a = tid & 63, rg = tid >> 6;
    float2 o;
    o.x = red[0][rg * 2][a] + red[1][rg * 2][a] + red[2][rg * 2][a] + red[3][rg * 2][a];
    o.y = red[0][rg * 2 + 1][a] + red[1][rg * 2 + 1][a] + red[2][rg * 2 + 1][a] + red[3][rg * 2 + 1][a];
    const size_t ba = (size_t)(b << 6) + a;
    *reinterpret_cast<float2*>(&partials[(ba * NHG + hg) * RELA + rt * RT + rg * 2]) = o;
}

// ---------------- K2b: s = sum partials (pre-negated); softmax+mask+renorm -> weight
__global__ __launch_bounds__(256) void k2b_softmax(const float* __restrict__ partials,
                                                   const int* __restrict__ masks,
                                                   float* __restrict__ weight) {
    const int tid = threadIdx.x;
    const int lane = tid & 63;
    const int wave = tid >> 6;
    const int ba = (blockIdx.x << 2) + wave;

    const float* pp = &partials[(size_t)ba * NHG * RELA];
    float s0 = 0.f, s1 = 0.f;
    #pragma unroll
    for (int hs = 0; hs < NHG; ++hs) {
        s0 += pp[hs * RELA + lane];
        s1 += pp[hs * RELA + lane + 64];
    }

    float m = fmaxf(s0, s1);
    #pragma unroll
    for (int off = 32; off > 0; off >>= 1)
        m = fmaxf(m, __shfl_xor(m, off));
    const float e0 = __expf(s0 - m), e1 = __expf(s1 - m);
    float sum = e0 + e1;
    #pragma unroll
    for (int off = 32; off > 0; off >>= 1)
        sum += __shfl_xor(sum, off);
    const float inv = 1.f / sum;
    const float m0 = (float)masks[(size_t)ba * RELA + lane];
    const float m1 = (float)masks[(size_t)ba * RELA + lane + 64];
    const float w0 = e0 * inv * m0;
    const float w1 = e1 * inv * m1;
    float ms = w0 + w1;
    #pragma unroll
    for (int off = 32; off > 0; off >>= 1)
        ms += __shfl_xor(ms, off);
    const float inv2 = 1.f / (ms + EPS_);
    weight[(size_t)ba * RELA + lane]      = w0 * inv2;
    weight[(size_t)ba * RELA + lane + 64] = w1 * inv2;
}

// ---------------- K3: out[b] = weight^T @ rela[b]; grid (B, RNN/64, 2), 256 thr
// a-split x2: each block does 32 a's x 64 d's -> 2 waves/SIMD occupancy
__global__ __launch_bounds__(256) void k3_wsum(const float* __restrict__ weight,
                                               const float* __restrict__ rela,
                                               float* __restrict__ out) {
    const int b = blockIdx.x;
    const int d_base = blockIdx.y << 6;
    const int ah = blockIdx.z;          // a-half: 0 or 1
    const int tid = threadIdx.x;
    const int col = tid & 15;           // float4 column in 64-d tile
    const int la0 = (tid >> 4) << 1;    // local a (2 per thread), 0..30

    __shared__ float ws_s[32][132];     // [la][r]
    __shared__ float rs[32 * 64];
    #pragma unroll
    for (int i = 0; i < 4; ++i) {       // stage 32 rows x 128 = 1024 float4
        const int fi = tid + (i << 8);
        const int a = fi >> 5, r0 = (fi & 31) << 2;
        *reinterpret_cast<float4*>(&ws_s[a][r0]) =
            *reinterpret_cast<const float4*>(&weight[((size_t)b * ATT + (ah << 5) + a) * RELA + r0]);
    }
    float4 acc[2] = {};
    for (int rc = 0; rc < 4; ++rc) {
        __syncthreads();
        #pragma unroll
        for (int i = 0; i < 2; ++i) {
            const int fi = tid + (i << 8);
            const int rr = fi >> 4, c = fi & 15;
            *reinterpret_cast<float4*>(&rs[(rr << 6) + (c << 2)]) =
                *reinterpret_cast<const float4*>(&rela[((size_t)b * RELA + (rc << 5) + rr) * RNN + d_base + (c << 2)]);
        }
        __syncthreads();
        #pragma unroll 8
        for (int rr = 0; rr < 32; ++rr) {
            const float4 x = *reinterpret_cast<const float4*>(&rs[(rr << 6) + (col << 2)]);
            const int r = (rc << 5) + rr;
            #pragma unroll
            for (int ai = 0; ai < 2; ++ai) {
                const float wv = ws_s[la0 + ai][r];
                acc[ai].x = fmaf(wv, x.x, acc[ai].x);
                acc[ai].y = fmaf(wv, x.y, acc[ai].y);
                acc[ai].z = fmaf(wv, x.z, acc[ai].z);
                acc[ai].w = fmaf(wv, x.w, acc[ai].w);
            }
        }
    }
    #pragma unroll
    for (int ai = 0; ai < 2; ++ai)
        *reinterpret_cast<float4*>(
            &out[((size_t)(b << 6) + (ah << 5) + la0 + ai) * RNN + d_base + (col << 2)]) = acc[ai];
}

extern "C" void kernel_launch(void* const* d_in, const int* in_sizes, int n_in,
                              void* d_out, int out_size, void* d_ws, size_t ws_size,
                              hipStream_t stream) {
    const float* obj_vecs = (const float*)d_in[0];
    const float* rela     = (const float*)d_in[1];
    const float* p_rela   = (const float*)d_in[2];
    const float* W_obj    = (const float*)d_in[3];
    const float* b_obj    = (const float*)d_in[4];
    const float* w_alpha  = (const float*)d_in[5];
    // d_in[6] (b_alpha): softmax-shift-invariant, unused
    const int*   masks    = (const int*)d_in[7];
    float* out = (float*)d_out;

    char* ws = (char*)d_ws;
    unsigned short* Abf = (unsigned short*)(ws);                 // [0, 2MB)
    unsigned short* WT  = (unsigned short*)(ws + (2u << 20));    // [2MB, 3MB)
    float* Eq           = (float*)(ws + (3u << 20));             // [3MB, 5MB)
    float* partials     = (float*)(ws + (5u << 20));             // [5MB, 9MB)
    float* weight       = (float*)(ws + (9u << 20));             // [9MB, 9.5MB)

    k0_pre<<<dim3(640), 256, 0, stream>>>(obj_vecs, W_obj, Abf, WT);
    k1_mfma<<<dim3(M_ / 32, HID / 32), 256, 0, stream>>>(Abf, WT, b_obj, Eq);
    k2a_scores<<<dim3(B_, NRT, NHG), 256, 0, stream>>>(Eq, p_rela, w_alpha, partials);
    k2b_softmax<<<dim3(M_ / 4), 256, 0, stream>>>(partials, masks, weight);
    k3_wsum<<<dim3(B_, RNN / 64, 2), 256, 0, stream>>>(weight, rela, out);
}

// Round 17
// 47.343 us; speedup vs baseline: 1.1884x; 1.0037x over previous
//
#include <hip/hip_runtime.h>

// GraphAttentionRela: B=16, ATT=64, RELA=128, RNN=1024, HID=512
// R12 verbatim (measured best: 47.5us, reproduced 47.52).
// Split-exp: tanh(p+q) = 1 - 2*rcp(exp2(K*p)*exp2(K*q)+1), K=2/ln2; score constants
// dropped (softmax shift-invariant); wws = -2*w_alpha so partials sum IS the score.
// K0 : A->bf16 | W->W^T bf16
// K1 : MFMA bf16 GEMM; epilogue Eq = exp2(K*(A@W+b_obj))
// K2a: stage exp2(K*p); partials[ba][hg][r] = sum_h (-2w_h)*rcp(Ep*Eq+1)
// K2b: s = sum_hg partials; softmax+mask+renorm -> weight[b][a][r]
// K3 : out[b] = weight^T @ rela[b], a-split x2
// WS (disjoint): Abf[0,2) WT[2,3) Eq[3,5) partials[5,9) weight[9,9.5) MB

constexpr int B_   = 16;
constexpr int ATT  = 64;
constexpr int RELA = 128;
constexpr int RNN  = 1024;
constexpr int HID  = 512;
constexpr int M_   = B_ * ATT;      // 1024
constexpr float EPS_ = 1e-8f;
constexpr float K2LN = 2.885390081777927f;   // 2/ln2
constexpr int RT  = 8;              // r per k2a block
constexpr int NRT = RELA / RT;      // 16
constexpr int HG  = 64;             // h per k2a block
constexpr int NHG = HID / HG;       // 8
constexpr int HW  = 16;             // h per wave

typedef short bf16x8 __attribute__((ext_vector_type(8)));
typedef float f32x4  __attribute__((ext_vector_type(4)));

__device__ __forceinline__ unsigned short f2bf(float f) {   // round-to-nearest-even
    unsigned u = __float_as_uint(f);
    u += 0x7FFFu + ((u >> 16) & 1u);
    return (unsigned short)(u >> 16);
}

// ---------------- K0: [0,512) A cast | [512,640) W transpose-cast
__global__ __launch_bounds__(256) void k0_pre(const float* __restrict__ A,
                                              const float* __restrict__ W,
                                              unsigned short* __restrict__ Abf,
                                              unsigned short* __restrict__ WT) {
    const int bid = blockIdx.x;
    const int tid = threadIdx.x;
    if (bid < 512) {
        const size_t idx = ((size_t)bid * 256 + tid) << 3;   // 8 floats
        const float4 f0 = *reinterpret_cast<const float4*>(&A[idx]);
        const float4 f1 = *reinterpret_cast<const float4*>(&A[idx + 4]);
        unsigned short us[8] = {f2bf(f0.x), f2bf(f0.y), f2bf(f0.z), f2bf(f0.w),
                                f2bf(f1.x), f2bf(f1.y), f2bf(f1.z), f2bf(f1.w)};
        *reinterpret_cast<uint4*>(&Abf[idx]) = *reinterpret_cast<uint4*>(us);
    } else {
        __shared__ float Ts[64][68];
        const int wb = bid - 512;
        const int k0 = (wb >> 3) << 6, n0 = (wb & 7) << 6;
        #pragma unroll
        for (int i = 0; i < 4; ++i) {
            const int r = (tid >> 4) + (i << 4);
            const int c4 = (tid & 15) << 2;
            *reinterpret_cast<float4*>(&Ts[r][c4]) =
                *reinterpret_cast<const float4*>(&W[(size_t)(k0 + r) * HID + n0 + c4]);
        }
        __syncthreads();
        const int n = tid >> 2, kq = (tid & 3) << 4;
        unsigned short us[16];
        #pragma unroll
        for (int e = 0; e < 16; ++e)
            us[e] = f2bf(Ts[kq + e][n]);
        unsigned short* dst = &WT[(size_t)(n0 + n) * RNN + k0 + kq];
        *reinterpret_cast<uint4*>(dst)     = *reinterpret_cast<uint4*>(us);
        *reinterpret_cast<uint4*>(dst + 8) = *reinterpret_cast<uint4*>(us + 8);
    }
}

// ---------------- K1: bf16 MFMA GEMM; epilogue Eq = exp2(K*(gemm+bias))
__global__ __launch_bounds__(256) void k1_mfma(const unsigned short* __restrict__ Abf,
                                               const unsigned short* __restrict__ WT,
                                               const float* __restrict__ b_obj,
                                               float* __restrict__ Eq) {
    const int tid = threadIdx.x;
    const int lane = tid & 63;
    const int wave = tid >> 6;
    const int m0 = (blockIdx.x << 5) + ((wave >> 1) << 4);
    const int n0 = (blockIdx.y << 5) + ((wave & 1) << 4);
    const int row  = lane & 15;
    const int koff = (lane >> 4) << 3;
    const unsigned short* ap = &Abf[(size_t)(m0 + row) * RNN + koff];
    const unsigned short* bp = &WT[(size_t)(n0 + row) * RNN + koff];
    f32x4 acc0 = {}, acc1 = {};
    #pragma unroll 4
    for (int k = 0; k < RNN; k += 64) {
        const bf16x8 a0 = *reinterpret_cast<const bf16x8*>(ap + k);
        const bf16x8 b0 = *reinterpret_cast<const bf16x8*>(bp + k);
        const bf16x8 a1 = *reinterpret_cast<const bf16x8*>(ap + k + 32);
        const bf16x8 b1 = *reinterpret_cast<const bf16x8*>(bp + k + 32);
        acc0 = __builtin_amdgcn_mfma_f32_16x16x32_bf16(a0, b0, acc0, 0, 0, 0);
        acc1 = __builtin_amdgcn_mfma_f32_16x16x32_bf16(a1, b1, acc1, 0, 0, 0);
    }
    const int dcol = lane & 15;
    const int drow0 = (lane >> 4) << 2;
    const float bias = b_obj[n0 + dcol];
    #pragma unroll
    for (int v = 0; v < 4; ++v)
        Eq[(size_t)(m0 + drow0 + v) * HID + n0 + dcol] =
            __builtin_amdgcn_exp2f((acc0[v] + acc1[v] + bias) * K2LN);
}

// ---------------- K2a: stage exp2(K*p); 4-op inner loop. grid (16,16,8)=2048, 256 thr
__global__ __launch_bounds__(256, 8) void k2a_scores(const float* __restrict__ Eq,
                                                     const float* __restrict__ p_rela,
                                                     const float* __restrict__ w_alpha,
                                                     float* __restrict__ partials) {
    const int b  = blockIdx.x;
    const int rt = blockIdx.y;
    const int hg = blockIdx.z;
    const int tid = threadIdx.x;
    const int lane = tid & 63;      // = a
    const int wave = tid >> 6;

    __shared__ float ps[RT][HG];        // 2 KB: exp2(K*p) tile
    __shared__ float wws[HG];           // -2*w_alpha for this hg
    __shared__ float red[4][RT][ATT];   // 8 KB, [wave][r][a] lane-contiguous

    if (tid < 128) {   // stage p tile with on-the-fly exp2: 8 rows x 16 float4
        const int row = tid >> 4, c4 = (tid & 15) << 2;
        float4 v = *reinterpret_cast<const float4*>(
            &p_rela[((size_t)b * RELA + rt * RT + row) * HID + hg * HG + c4]);
        v.x = __builtin_amdgcn_exp2f(v.x * K2LN);
        v.y = __builtin_amdgcn_exp2f(v.y * K2LN);
        v.z = __builtin_amdgcn_exp2f(v.z * K2LN);
        v.w = __builtin_amdgcn_exp2f(v.w * K2LN);
        *reinterpret_cast<float4*>(&ps[row][c4]) = v;
    } else if (tid < 144) {
        const int c4 = (tid - 128) << 2;
        float4 w = *reinterpret_cast<const float4*>(&w_alpha[hg * HG + c4]);
        w.x *= -2.f; w.y *= -2.f; w.z *= -2.f; w.w *= -2.f;
        *reinterpret_cast<float4*>(&wws[c4]) = w;
    }
    const int hbase = hg * HG + wave * HW;
    float4 eq[4];
    #pragma unroll
    for (int i = 0; i < 4; ++i)
        eq[i] = *reinterpret_cast<const float4*>(&Eq[(size_t)((b << 6) + lane) * HID + hbase + (i << 2)]);
    __syncthreads();

    float acc[RT] = {};
    #pragma unroll
    for (int i = 0; i < 4; ++i) {
        const float qq[4] = {eq[i].x, eq[i].y, eq[i].z, eq[i].w};
        const float4 w4 = *reinterpret_cast<const float4*>(&wws[wave * HW + (i << 2)]);  // broadcast
        const float ww[4] = {w4.x, w4.y, w4.z, w4.w};
        #pragma unroll
        for (int r = 0; r < RT; ++r) {
            const float4 p4 = *reinterpret_cast<const float4*>(&ps[r][wave * HW + (i << 2)]);  // broadcast
            const float pp[4] = {p4.x, p4.y, p4.z, p4.w};
            #pragma unroll
            for (int j = 0; j < 4; ++j) {
                const float e = pp[j] * qq[j];                       // exp2(K*(p+q))
                acc[r] = fmaf(ww[j], __builtin_amdgcn_rcpf(e + 1.f), acc[r]);
            }
        }
    }

    #pragma unroll
    for (int r = 0; r < RT; ++r)
        red[wave][r][lane] = acc[r];    // conflict-free
    __syncthreads();

    const int a = tid & 63, rg = tid >> 6;
    float2 o;
    o.x = red[0][rg * 2][a] + red[1][rg * 2][a] + red[2][rg * 2][a] + red[3][rg * 2][a];
    o.y = red[0][rg * 2 + 1][a] + red[1][rg * 2 + 1][a] + red[2][rg * 2 + 1][a] + red[3][rg * 2 + 1][a];
    const size_t ba = (size_t)(b << 6) + a;
    *reinterpret_cast<float2*>(&partials[(ba * NHG + hg) * RELA + rt * RT + rg * 2]) = o;
}

// ---------------- K2b: s = sum partials (pre-negated); softmax+mask+renorm -> weight
__global__ __launch_bounds__(256) void k2b_softmax(const float* __restrict__ partials,
                                                   const int* __restrict__ masks,
                                                   float* __restrict__ weight) {
    const int tid = threadIdx.x;
    const int lane = tid & 63;
    const int wave = tid >> 6;
    const int ba = (blockIdx.x << 2) + wave;

    const float* pp = &partials[(size_t)ba * NHG * RELA];
    float s0 = 0.f, s1 = 0.f;
    #pragma unroll
    for (int hs = 0; hs < NHG; ++hs) {
        s0 += pp[hs * RELA + lane];
        s1 += pp[hs * RELA + lane + 64];
    }

    float m = fmaxf(s0, s1);
    #pragma unroll
    for (int off = 32; off > 0; off >>= 1)
        m = fmaxf(m, __shfl_xor(m, off));
    const float e0 = __expf(s0 - m), e1 = __expf(s1 - m);
    float sum = e0 + e1;
    #pragma unroll
    for (int off = 32; off > 0; off >>= 1)
        sum += __shfl_xor(sum, off);
    const float inv = 1.f / sum;
    const float m0 = (float)masks[(size_t)ba * RELA + lane];
    const float m1 = (float)masks[(size_t)ba * RELA + lane + 64];
    const float w0 = e0 * inv * m0;
    const float w1 = e1 * inv * m1;
    float ms = w0 + w1;
    #pragma unroll
    for (int off = 32; off > 0; off >>= 1)
        ms += __shfl_xor(ms, off);
    const float inv2 = 1.f / (ms + EPS_);
    weight[(size_t)ba * RELA + lane]      = w0 * inv2;
    weight[(size_t)ba * RELA + lane + 64] = w1 * inv2;
}

// ---------------- K3: out[b] = weight^T @ rela[b]; grid (B, RNN/64, 2), 256 thr
// a-split x2: each block does 32 a's x 64 d's -> 2 waves/SIMD occupancy
__global__ __launch_bounds__(256) void k3_wsum(const float* __restrict__ weight,
                                               const float* __restrict__ rela,
                                               float* __restrict__ out) {
    const int b = blockIdx.x;
    const int d_base = blockIdx.y << 6;
    const int ah = blockIdx.z;          // a-half: 0 or 1
    const int tid = threadIdx.x;
    const int col = tid & 15;           // float4 column in 64-d tile
    const int la0 = (tid >> 4) << 1;    // local a (2 per thread), 0..30

    __shared__ float ws_s[32][132];     // [la][r]
    __shared__ float rs[32 * 64];
    #pragma unroll
    for (int i = 0; i < 4; ++i) {       // stage 32 rows x 128 = 1024 float4
        const int fi = tid + (i << 8);
        const int a = fi >> 5, r0 = (fi & 31) << 2;
        *reinterpret_cast<float4*>(&ws_s[a][r0]) =
            *reinterpret_cast<const float4*>(&weight[((size_t)b * ATT + (ah << 5) + a) * RELA + r0]);
    }
    float4 acc[2] = {};
    for (int rc = 0; rc < 4; ++rc) {
        __syncthreads();
        #pragma unroll
        for (int i = 0; i < 2; ++i) {
            const int fi = tid + (i << 8);
            const int rr = fi >> 4, c = fi & 15;
            *reinterpret_cast<float4*>(&rs[(rr << 6) + (c << 2)]) =
                *reinterpret_cast<const float4*>(&rela[((size_t)b * RELA + (rc << 5) + rr) * RNN + d_base + (c << 2)]);
        }
        __syncthreads();
        #pragma unroll 8
        for (int rr = 0; rr < 32; ++rr) {
            const float4 x = *reinterpret_cast<const float4*>(&rs[(rr << 6) + (col << 2)]);
            const int r = (rc << 5) + rr;
            #pragma unroll
            for (int ai = 0; ai < 2; ++ai) {
                const float wv = ws_s[la0 + ai][r];
                acc[ai].x = fmaf(wv, x.x, acc[ai].x);
                acc[ai].y = fmaf(wv, x.y, acc[ai].y);
                acc[ai].z = fmaf(wv, x.z, acc[ai].z);
                acc[ai].w = fmaf(wv, x.w, acc[ai].w);
            }
        }
    }
    #pragma unroll
    for (int ai = 0; ai < 2; ++ai)
        *reinterpret_cast<float4*>(
            &out[((size_t)(b << 6) + (ah << 5) + la0 + ai) * RNN + d_base + (col << 2)]) = acc[ai];
}

extern "C" void kernel_launch(void* const* d_in, const int* in_sizes, int n_in,
                              void* d_out, int out_size, void* d_ws, size_t ws_size,
                              hipStream_t stream) {
    const float* obj_vecs = (const float*)d_in[0];
    const float* rela     = (const float*)d_in[1];
    const float* p_rela   = (const float*)d_in[2];
    const float* W_obj    = (const float*)d_in[3];
    const float* b_obj    = (const float*)d_in[4];
    const float* w_alpha  = (const float*)d_in[5];
    // d_in[6] (b_alpha): softmax-shift-invariant, unused
    const int*   masks    = (const int*)d_in[7];
    float* out = (float*)d_out;

    char* ws = (char*)d_ws;
    unsigned short* Abf = (unsigned short*)(ws);                 // [0, 2MB)
    unsigned short* WT  = (unsigned short*)(ws + (2u << 20));    // [2MB, 3MB)
    float* Eq           = (float*)(ws + (3u << 20));             // [3MB, 5MB)
    float* partials     = (float*)(ws + (5u << 20));             // [5MB, 9MB)
    float* weight       = (float*)(ws + (9u << 20));             // [9MB, 9.5MB)

    k0_pre<<<dim3(640), 256, 0, stream>>>(obj_vecs, W_obj, Abf, WT);
    k1_mfma<<<dim3(M_ / 32, HID / 32), 256, 0, stream>>>(Abf, WT, b_obj, Eq);
    k2a_scores<<<dim3(B_, NRT, NHG), 256, 0, stream>>>(Eq, p_rela, w_alpha, partials);
    k2b_softmax<<<dim3(M_ / 4), 256, 0, stream>>>(partials, masks, weight);
    k3_wsum<<<dim3(B_, RNN / 64, 2), 256, 0, stream>>>(weight, rela, out);
}